// Round 10
// baseline (85.004 us; speedup 1.0000x reference)
//
#include <hip/hip_runtime.h>

#define N_PIX   65536
#define N_GAUSS 2048

typedef __bf16 bf16x8 __attribute__((ext_vector_type(8)));
typedef float  f32x4  __attribute__((ext_vector_type(4)));

union BF8U { uint4 u; bf16x8 h; };
__device__ inline bf16x8 as_bf(uint4 u) { BF8U x; x.u = u; return x.h; }

__device__ inline unsigned short bfbits(float f) {
  __bf16 h = (__bf16)f;
  return __builtin_bit_cast(unsigned short, h);
}
__device__ inline float bf2f(unsigned short b) {
  return (float)__builtin_bit_cast(__bf16, b);
}
__device__ inline unsigned pkb(unsigned short a, unsigned short b) {
  return (unsigned)a | ((unsigned)b << 16);
}
__device__ inline unsigned pk2f(float a, float b) {
  return pkb(bfbits(a), bfbits(b));
}

// ---------------------------------------------------------------------------
// K-layout (shared by P and G, K=32, 24 used):
//   k0-5 : Ghi*Phi   k6-11: Glo*Phi   k12-17: Ghi*Plo   k18-23: Glo*Plo
// so  q = sum_i (Ghi+Glo)_i * (Phi+Plo)_i  — full hi/lo split product.
// Coefs include -0.5*log2(e) so w = exp2(q) == exp(-0.5*maha).
//
// ws layout: [0, 8192)   uint4 : GQ frags, 128 tiles x 64 lanes x 16B (A-op)
//            [8192,12288) uint4 : PVC frags, 64 tiles x 64 lanes x 16B (B-op)
// ---------------------------------------------------------------------------

__global__ __launch_bounds__(256) void prep_kernel(
    const float* __restrict__ mus, const float* __restrict__ covs,
    const float* __restrict__ cols, uint4* __restrict__ ws) {
  int tid = blockIdx.x * 256 + threadIdx.x;
  if (tid < 8192) {
    // GQ fragment: A-operand of q-MFMA. lane row = gauss (lane&15),
    // k = (lane>>4)*8 + j.  G row = [Chi0-5, Clo0-5, Chi0-5, Clo0-5, 0...]
    int lane = tid & 63;
    int tile = tid >> 6;
    int grp  = lane >> 4;
    int g    = tile * 16 + (lane & 15);
    float c00 = covs[4*g+0], c01 = covs[4*g+1];
    float c10 = covs[4*g+2], c11 = covs[4*g+3];
    float inv_det = 1.0f / (c00*c11 - c01*c10);
    float ia =  c11 * inv_det;
    float ib = -c01 * inv_det;
    float ic =  c00 * inv_det;
    float mx = mus[2*g+0], my = mus[2*g+1];
    const float kk = -0.7213475204444817f;   // -0.5*log2(e)
    float coef[6];
    coef[0] = kk * ia;
    coef[1] = kk * 2.0f * ib;
    coef[2] = kk * ic;
    coef[3] = -2.0f * kk * (ia*mx + ib*my);
    coef[4] = -2.0f * kk * (ib*mx + ic*my);
    coef[5] = kk * (ia*mx*mx + 2.0f*ib*mx*my + ic*my*my);
    unsigned short ch[6], cl[6];
    #pragma unroll
    for (int i = 0; i < 6; ++i) {
      ch[i] = bfbits(coef[i]);
      cl[i] = bfbits(coef[i] - bf2f(ch[i]));
    }
    uint4 v = make_uint4(0,0,0,0);
    if (grp == 0)      v = make_uint4(pkb(ch[0],ch[1]), pkb(ch[2],ch[3]), pkb(ch[4],ch[5]), pkb(cl[0],cl[1]));
    else if (grp == 1) v = make_uint4(pkb(cl[2],cl[3]), pkb(cl[4],cl[5]), pkb(ch[0],ch[1]), pkb(ch[2],ch[3]));
    else if (grp == 2) v = make_uint4(pkb(ch[4],ch[5]), pkb(cl[0],cl[1]), pkb(cl[2],cl[3]), pkb(cl[4],cl[5]));
    ws[tid] = v;
  } else if (tid < 12288) {
    // PVC fragment: B-operand of PV MFMA (K=32 gauss, N=16 rgb, 3 used).
    // lane col = rgb (lane&15), k = (lane>>4)*8 + j.
    int t2   = tid - 8192;
    int lane = t2 & 63;
    int tile = t2 >> 6;
    int rgb  = lane & 15;
    int kb   = (lane >> 4) * 8;
    uint4 v = make_uint4(0,0,0,0);
    if (rgb < 3) {
      unsigned short b[8];
      #pragma unroll
      for (int j = 0; j < 8; ++j)
        b[j] = bfbits(cols[(tile*32 + kb + j)*3 + rgb]);
      v = make_uint4(pkb(b[0],b[1]), pkb(b[2],b[3]), pkb(b[4],b[5]), pkb(b[6],b[7]));
    }
    ws[8192 + t2] = v;
  }
}

// ---------------------------------------------------------------------------
// Render: 1024 blocks x 512 threads (8 waves); 16 pixels/wave, 128/block.
// Gaussian 2-way split: block half h handles gaussians [h*1024, h*1024+1024)
// (4 chunks of 256), accumulating into out via f32 atomics. 4 blocks/CU =
// 32 waves/CU (max occupancy) to hide the per-step serial chain:
// q-MFMA -> exp2 -> pack -> W ds_write -> lgkmcnt -> ds_read -> PV MFMA.
// cols B-fragments load straight from global (L2-resident) per step.
// LDS map (uint4 idx): [0,1024) GQ chunk, [1024,1536) W (8 waves x 1KB).
// ---------------------------------------------------------------------------
__global__ __launch_bounds__(512, 8) void render_kernel(
    const float2* __restrict__ x, const uint4* __restrict__ ws,
    float* __restrict__ out) {
  __shared__ uint4 smem[1536];                  // 24 KB
  const uint4* gq  = ws;                        // 8192 uint4
  const uint4* pvc = ws + 8192;                 // 4096 uint4

  int tid  = threadIdx.x;
  int lane = tid & 63, wave = tid >> 6;
  int c    = lane & 15, grp = lane >> 4;
  int pixblk = blockIdx.x & 511;
  int half   = blockIdx.x >> 9;                 // 0 or 1: gaussian half
  int cbase  = half * 4;                        // first 256-gauss chunk
  int wpix = pixblk * 128 + wave * 16;

  // P fragment: B-operand of q-MFMA. lane col = pix (lane&15),
  // k = grp*8 + j.  P col = [Phi0-5, Phi0-5, Plo0-5, Plo0-5, 0...]
  float2 p = x[wpix + c];
  float mono[6] = {p.x*p.x, p.x*p.y, p.y*p.y, p.x, p.y, 1.0f};
  unsigned short ph[6], pl[6];
  #pragma unroll
  for (int i = 0; i < 6; ++i) {
    ph[i] = bfbits(mono[i]);
    pl[i] = bfbits(mono[i] - bf2f(ph[i]));
  }
  uint4 pv4 = make_uint4(0,0,0,0);
  if (grp == 0)      pv4 = make_uint4(pkb(ph[0],ph[1]), pkb(ph[2],ph[3]), pkb(ph[4],ph[5]), pkb(ph[0],ph[1]));
  else if (grp == 1) pv4 = make_uint4(pkb(ph[2],ph[3]), pkb(ph[4],ph[5]), pkb(pl[0],pl[1]), pkb(pl[2],pl[3]));
  else if (grp == 2) pv4 = make_uint4(pkb(pl[4],pl[5]), pkb(pl[0],pl[1]), pkb(pl[2],pl[3]), pkb(pl[4],pl[5]));
  bf16x8 pf = as_bf(pv4);

  // Wave-private W buffer: [pix 16][gauss 32] bf16 (1KB), XOR-swizzled so
  // both the b64 writes and b128 reads sit at the bank floor.
  char* Wb = (char*)smem + 16384 + (wave << 10);
  int b0 = c*64 + grp*8;          // write, q-tile parity 0 (gauss 4*grp+0..3)
  int b1 = c*64 + 32 + grp*8;     // write, parity 1
  int br = c*64 + grp*16;         // read: pix=c, gauss 8*grp..+7
  uint2* wp0 = (uint2*)(Wb + (b0 ^ (((b0 >> 7) & 3) << 4)));
  uint2* wp1 = (uint2*)(Wb + (b1 ^ (((b1 >> 7) & 3) << 4)));
  const uint4* rp = (const uint4*)(Wb + (br ^ (((br >> 7) & 3) << 4)));

  f32x4 acc  = {0.f, 0.f, 0.f, 0.f};
  const f32x4 zero = {0.f, 0.f, 0.f, 0.f};

  // Software-pipelined GQ staging: loads for chunk k+1 issue before compute(k).
  uint4 s0 = gq[cbase*1024 + tid], s1 = gq[cbase*1024 + 512 + tid];
  for (int chk = 0; chk < 4; ++chk) {
    __syncthreads();                       // all waves done reading prev chunk
    smem[tid] = s0; smem[512 + tid] = s1;
    __syncthreads();
    if (chk < 3) {
      s0 = gq[(cbase+chk+1)*1024 + tid];
      s1 = gq[(cbase+chk+1)*1024 + 512 + tid];
    }
    #pragma unroll
    for (int pr = 0; pr < 8; ++pr) {       // 8 x 32 gaussians
      uint4 ga = smem[(2*pr+0)*64 + lane];
      uint4 gb = smem[(2*pr+1)*64 + lane];
      uint4 cf = pvc[(cbase+chk)*512 + pr*64 + lane];   // L2-resident
      // swapped QK^T: D[gauss][pix] (row=gauss=grp*4+reg, col=pix=c)
      f32x4 q0 = __builtin_amdgcn_mfma_f32_16x16x32_bf16(as_bf(ga), pf, zero, 0, 0, 0);
      f32x4 q1 = __builtin_amdgcn_mfma_f32_16x16x32_bf16(as_bf(gb), pf, zero, 0, 0, 0);
      uint2 w0, w1;
      w0.x = pk2f(__builtin_amdgcn_exp2f(q0[0]), __builtin_amdgcn_exp2f(q0[1]));
      w0.y = pk2f(__builtin_amdgcn_exp2f(q0[2]), __builtin_amdgcn_exp2f(q0[3]));
      w1.x = pk2f(__builtin_amdgcn_exp2f(q1[0]), __builtin_amdgcn_exp2f(q1[1]));
      w1.y = pk2f(__builtin_amdgcn_exp2f(q1[2]), __builtin_amdgcn_exp2f(q1[3]));
      *wp0 = w0;                           // W[pix=c][gauss 4g+0..3]
      *wp1 = w1;                           // W[pix=c][16 + 4g+0..3]
      asm volatile("s_waitcnt lgkmcnt(0)" ::: "memory");
      uint4 wf = *rp;                      // A-op: w[pix=c][gauss 8*grp..+7]
      // PV: D[pix][rgb] += w * colsT  (row=pix=grp*4+reg, col=rgb=c)
      acc = __builtin_amdgcn_mfma_f32_16x16x32_bf16(as_bf(wf), as_bf(cf), acc, 0, 0, 0);
    }
  }
  if (c < 3) {
    int pix = wpix + grp * 4;
    unsafeAtomicAdd(&out[(pix+0)*3 + c], acc[0]);
    unsafeAtomicAdd(&out[(pix+1)*3 + c], acc[1]);
    unsafeAtomicAdd(&out[(pix+2)*3 + c], acc[2]);
    unsafeAtomicAdd(&out[(pix+3)*3 + c], acc[3]);
  }
}

extern "C" void kernel_launch(void* const* d_in, const int* in_sizes, int n_in,
                              void* d_out, int out_size, void* d_ws, size_t ws_size,
                              hipStream_t stream) {
  const float* x    = (const float*)d_in[0];   // [N_PIX, 2]
  const float* mus  = (const float*)d_in[1];   // [N_GAUSS, 2]
  const float* covs = (const float*)d_in[2];   // [N_GAUSS, 2, 2]
  const float* cols = (const float*)d_in[3];   // [N_GAUSS, 3]
  float* out = (float*)d_out;                  // [N_PIX, 3]
  uint4* ws  = (uint4*)d_ws;                   // 192 KB of fragments

  // halves accumulate atomically -> zero the poisoned output first
  hipMemsetAsync(out, 0, (size_t)out_size * sizeof(float), stream);

  prep_kernel<<<48, 256, 0, stream>>>(mus, covs, cols, ws);
  render_kernel<<<1024, 512, 0, stream>>>((const float2*)x, ws, out);
}

// Round 12
// 82.157 us; speedup vs baseline: 1.0347x; 1.0347x over previous
//
#include <hip/hip_runtime.h>

#define N_PIX   65536
#define N_GAUSS 2048

typedef __bf16 bf16x8 __attribute__((ext_vector_type(8)));
typedef float  f32x4  __attribute__((ext_vector_type(4)));

union BF8U { uint4 u; bf16x8 h; };
__device__ inline bf16x8 as_bf(uint4 u) { BF8U x; x.u = u; return x.h; }

__device__ inline unsigned short bfbits(float f) {
  __bf16 h = (__bf16)f;
  return __builtin_bit_cast(unsigned short, h);
}
__device__ inline float bf2f(unsigned short b) {
  return (float)__builtin_bit_cast(__bf16, b);
}
__device__ inline unsigned pkb(unsigned short a, unsigned short b) {
  return (unsigned)a | ((unsigned)b << 16);
}
__device__ inline unsigned pk2f(float a, float b) {
  return pkb(bfbits(a), bfbits(b));
}

// ---------------------------------------------------------------------------
// q-MFMA K-layout (shared by P and G, K=32, 24 used):
//   k0-5 : Ghi*Phi   k6-11: Glo*Phi   k12-17: Ghi*Plo   k18-23: Glo*Plo
// so  q = sum_i (Ghi+Glo)_i * (Phi+Plo)_i  — full hi/lo split product.
// Coefs include -0.5*log2(e) so w = exp2(q) == exp(-0.5*maha).
//
// PV has NO transpose: the swapped q-MFMA leaves lane (pix=c, grp) holding
// w for gauss {4grp+0..3} (q0 regs) and {16+4grp+0..3} (q1 regs). Packed as
// {q0[0],q0[1]},{q0[2],q0[3]},{q1[0],q1[1]},{q1[2],q1[3]} this IS a valid
// PV B-operand (col=pix, k=grp*8+j) under the K-order
//   pi(grp*8+j) = (j<4) ? 4*grp+j : 16+4*grp+(j-4)   (a bijection on 0..31).
// prep packs the cols A-operand (row=rgb, k) with gauss pi(k), so
// D2[rgb][pix] = sum_g cols[g][rgb] * w[g][pix] exactly. rgb rows 3..15 are
// zero-padded, so only grp==0 lanes carry output.
//
// ws layout: [0, 8192)   uint4 : GQ frags, 128 tiles x 64 lanes x 16B (A-op)
//            [8192,12288) uint4 : PVC frags (pi-ordered cols A-op), 64 tiles
// ---------------------------------------------------------------------------

__global__ __launch_bounds__(256) void prep_kernel(
    const float* __restrict__ mus, const float* __restrict__ covs,
    const float* __restrict__ cols, uint4* __restrict__ ws) {
  int tid = blockIdx.x * 256 + threadIdx.x;
  if (tid < 8192) {
    // GQ fragment: A-operand of q-MFMA. lane row = gauss (lane&15),
    // k = (lane>>4)*8 + j.  G row = [Chi0-5, Clo0-5, Chi0-5, Clo0-5, 0...]
    int lane = tid & 63;
    int tile = tid >> 6;
    int grp  = lane >> 4;
    int g    = tile * 16 + (lane & 15);
    float c00 = covs[4*g+0], c01 = covs[4*g+1];
    float c10 = covs[4*g+2], c11 = covs[4*g+3];
    float inv_det = 1.0f / (c00*c11 - c01*c10);
    float ia =  c11 * inv_det;
    float ib = -c01 * inv_det;
    float ic =  c00 * inv_det;
    float mx = mus[2*g+0], my = mus[2*g+1];
    const float kk = -0.7213475204444817f;   // -0.5*log2(e)
    float coef[6];
    coef[0] = kk * ia;
    coef[1] = kk * 2.0f * ib;
    coef[2] = kk * ic;
    coef[3] = -2.0f * kk * (ia*mx + ib*my);
    coef[4] = -2.0f * kk * (ib*mx + ic*my);
    coef[5] = kk * (ia*mx*mx + 2.0f*ib*mx*my + ic*my*my);
    unsigned short ch[6], cl[6];
    #pragma unroll
    for (int i = 0; i < 6; ++i) {
      ch[i] = bfbits(coef[i]);
      cl[i] = bfbits(coef[i] - bf2f(ch[i]));
    }
    uint4 v = make_uint4(0,0,0,0);
    if (grp == 0)      v = make_uint4(pkb(ch[0],ch[1]), pkb(ch[2],ch[3]), pkb(ch[4],ch[5]), pkb(cl[0],cl[1]));
    else if (grp == 1) v = make_uint4(pkb(cl[2],cl[3]), pkb(cl[4],cl[5]), pkb(ch[0],ch[1]), pkb(ch[2],ch[3]));
    else if (grp == 2) v = make_uint4(pkb(ch[4],ch[5]), pkb(cl[0],cl[1]), pkb(cl[2],cl[3]), pkb(cl[4],cl[5]));
    ws[tid] = v;
  } else if (tid < 12288) {
    // PVC fragment: A-operand of PV MFMA. lane row = rgb (lane&15, 3 used),
    // k = (lane>>4)*8 + j, gauss id at k-slot = pi(k) (see header).
    int t2   = tid - 8192;
    int lane = t2 & 63;
    int tile = t2 >> 6;
    int rgb  = lane & 15;
    int grp  = lane >> 4;
    uint4 v = make_uint4(0,0,0,0);
    if (rgb < 3) {
      unsigned short b[8];
      #pragma unroll
      for (int j = 0; j < 8; ++j) {
        int sig = 4*grp + (j & 3) + ((j >> 2) ? 16 : 0);   // pi(grp*8+j)
        b[j] = bfbits(cols[(tile*32 + sig)*3 + rgb]);
      }
      v = make_uint4(pkb(b[0],b[1]), pkb(b[2],b[3]), pkb(b[4],b[5]), pkb(b[6],b[7]));
    }
    ws[8192 + t2] = v;
  }
}

// ---------------------------------------------------------------------------
// Render: 512 blocks x 512 threads (8 waves); 16 pixels/wave, 128/block.
// Per chunk of 256 gaussians: GQ staged in LDS (16 KB, pipelined); pi-ordered
// cols A-fragments in regs from global (L2-resident). Per 32-gauss step:
// 2 swapped q-MFMAs -> exp2 -> bf16 pack -> PV MFMA DIRECTLY (w is already a
// valid B-operand). No transpose, no W LDS round-trip, no lgkmcnt drain.
// ---------------------------------------------------------------------------
__global__ __launch_bounds__(512, 4) void render_kernel(
    const float2* __restrict__ x, const uint4* __restrict__ ws,
    float* __restrict__ out) {
  __shared__ uint4 smem[1024];                  // 16 KB: one GQ chunk
  const uint4* gq  = ws;                        // 8192 uint4
  const uint4* pvc = ws + 8192;                 // 4096 uint4

  int tid  = threadIdx.x;
  int lane = tid & 63;
  int c    = lane & 15, grp = lane >> 4;
  int wave = tid >> 6;
  int wpix = blockIdx.x * 128 + wave * 16;

  // P fragment: B-operand of q-MFMA. lane col = pix (lane&15),
  // k = grp*8 + j.  P col = [Phi0-5, Phi0-5, Plo0-5, Plo0-5, 0...]
  float2 p = x[wpix + c];
  float mono[6] = {p.x*p.x, p.x*p.y, p.y*p.y, p.x, p.y, 1.0f};
  unsigned short ph[6], pl[6];
  #pragma unroll
  for (int i = 0; i < 6; ++i) {
    ph[i] = bfbits(mono[i]);
    pl[i] = bfbits(mono[i] - bf2f(ph[i]));
  }
  uint4 pv4 = make_uint4(0,0,0,0);
  if (grp == 0)      pv4 = make_uint4(pkb(ph[0],ph[1]), pkb(ph[2],ph[3]), pkb(ph[4],ph[5]), pkb(ph[0],ph[1]));
  else if (grp == 1) pv4 = make_uint4(pkb(ph[2],ph[3]), pkb(ph[4],ph[5]), pkb(pl[0],pl[1]), pkb(pl[2],pl[3]));
  else if (grp == 2) pv4 = make_uint4(pkb(pl[4],pl[5]), pkb(pl[0],pl[1]), pkb(pl[2],pl[3]), pkb(pl[4],pl[5]));
  bf16x8 pf = as_bf(pv4);

  f32x4 acc  = {0.f, 0.f, 0.f, 0.f};
  const f32x4 zero = {0.f, 0.f, 0.f, 0.f};

  // Software-pipelined GQ staging: loads for chunk k+1 issue before compute(k).
  uint4 s0 = gq[tid], s1 = gq[512 + tid];
  for (int chk = 0; chk < 8; ++chk) {
    __syncthreads();                       // all waves done reading prev chunk
    smem[tid] = s0; smem[512 + tid] = s1;
    __syncthreads();
    if (chk < 7) {
      s0 = gq[(chk+1)*1024 + tid];
      s1 = gq[(chk+1)*1024 + 512 + tid];
    }
    // pi-ordered cols A-fragments for this chunk (L2-resident), hoisted so
    // latency hides under the 8 compute steps.
    uint4 cf[8];
    #pragma unroll
    for (int t = 0; t < 8; ++t)
      cf[t] = pvc[chk*512 + t*64 + lane];
    #pragma unroll
    for (int pr = 0; pr < 8; ++pr) {       // 8 x 32 gaussians
      uint4 ga = smem[(2*pr+0)*64 + lane];
      uint4 gb = smem[(2*pr+1)*64 + lane];
      // swapped QK^T: D[gauss][pix] (row=gauss=grp*4+reg, col=pix=c)
      f32x4 q0 = __builtin_amdgcn_mfma_f32_16x16x32_bf16(as_bf(ga), pf, zero, 0, 0, 0);
      f32x4 q1 = __builtin_amdgcn_mfma_f32_16x16x32_bf16(as_bf(gb), pf, zero, 0, 0, 0);
      // lane(c,grp): w for gauss {4grp+0..3} (q0) and {16+4grp+0..3} (q1),
      // pixel c — already a valid PV B-operand under pi (see header).
      unsigned w0 = pk2f(__builtin_amdgcn_exp2f(q0[0]), __builtin_amdgcn_exp2f(q0[1]));
      unsigned w1 = pk2f(__builtin_amdgcn_exp2f(q0[2]), __builtin_amdgcn_exp2f(q0[3]));
      unsigned w2 = pk2f(__builtin_amdgcn_exp2f(q1[0]), __builtin_amdgcn_exp2f(q1[1]));
      unsigned w3 = pk2f(__builtin_amdgcn_exp2f(q1[2]), __builtin_amdgcn_exp2f(q1[3]));
      uint4 wf = make_uint4(w0, w1, w2, w3);
      // PV: D2[rgb][pix] += colsT(pi) * w   (row=rgb=grp*4+reg, col=pix=c)
      acc = __builtin_amdgcn_mfma_f32_16x16x32_bf16(as_bf(cf[pr]), as_bf(wf), acc, 0, 0, 0);
    }
  }
  // D2 rows 0..2 = rgb live in grp==0 lanes (reg 0..2); rows 3..15 are zero.
  if (grp == 0) {
    int pix = wpix + c;
    out[pix*3 + 0] = acc[0];
    out[pix*3 + 1] = acc[1];
    out[pix*3 + 2] = acc[2];
  }
}

extern "C" void kernel_launch(void* const* d_in, const int* in_sizes, int n_in,
                              void* d_out, int out_size, void* d_ws, size_t ws_size,
                              hipStream_t stream) {
  const float* x    = (const float*)d_in[0];   // [N_PIX, 2]
  const float* mus  = (const float*)d_in[1];   // [N_GAUSS, 2]
  const float* covs = (const float*)d_in[2];   // [N_GAUSS, 2, 2]
  const float* cols = (const float*)d_in[3];   // [N_GAUSS, 3]
  float* out = (float*)d_out;                  // [N_PIX, 3]
  uint4* ws  = (uint4*)d_ws;                   // 192 KB of fragments

  prep_kernel<<<48, 256, 0, stream>>>(mus, covs, cols, ws);
  render_kernel<<<512, 512, 0, stream>>>((const float2*)x, ws, out);
}